// Round 1
// baseline (229.426 us; speedup 1.0000x reference)
//
#include <hip/hip_runtime.h>

// DAGConstraintLayer: out[b,i] = sigmoid(min over root-to-i chain of x[b,i]).
// R3 staged 32 rows through LDS (coalesced f4 in/out) with an in-place
// register DFS. rocprof R3: no pipe >30% busy -> latency-bound. Cause: the
// in-place LDS DFS (write node, read child) can't be disambiguated by the
// compiler (VGPR_Count=16, no hoisting) -> ~15 serial LDS-latency hops
// (~2000 cy) per compute phase. R4: read ALL 18 needed LDS values up front
// (addresses are static per thread), compute 15 path-mins + sigmoids in
// registers, then write -> 1 LDS latency instead of 15. Stage-in switched to
// global_load_lds dwordx4 (layout is exactly wave-uniform base + lane*16).
// 16.25 KB LDS -> 8 blocks/CU -> 32 waves/CU.

#define NODES 127
#define RPB   32                 // rows per block
#define BLOCK 256
#define TILE_F4 (RPB * NODES / 4)   // 1016

__device__ __forceinline__ float sigf(float v) {
    return 1.0f / (1.0f + __expf(-v));
}

__global__ __launch_bounds__(BLOCK, 8) void dag_kernel(const float* __restrict__ x,
                                                       float* __restrict__ out) {
    __shared__ float buf[RPB * NODES];          // 16,256 B

    const size_t base = (size_t)blockIdx.x * (RPB * NODES);
    const int t = threadIdx.x;
    const int wid = t >> 6;                      // wave id 0..3

    // ---- stage-in: global -> LDS direct DMA, linear layout (lane i of the
    // wave lands at base + i*16, which is exactly element idx) ----
    const float4* __restrict__ src = (const float4*)(x + base);
    #pragma unroll
    for (int k = 0; k < 4; ++k) {
        const int idx = t + k * BLOCK;
        if (idx < TILE_F4) {                     // k<3: always true; k==3: lanes of wave 3 masked
            __builtin_amdgcn_global_load_lds(
                (const __attribute__((address_space(1))) unsigned int*)(src + idx),
                (__attribute__((address_space(3))) unsigned int*)
                    ((char*)buf + (size_t)(k * BLOCK + wid * 64) * 16),
                16, 0, 0);
        }
    }
    __syncthreads();                             // waits vmcnt(0) -> LDS populated

    // ---- compute: 8 threads per row, one depth-3 subtree each ----
    const int rl = t >> 3;                       // local row 0..31
    const int s  = t & 7;                        // subtree id 0..7
    const int o  = rl * NODES;
    const int m3 = 7 + s;                        // subtree root (depth 3)
    const int m2 = (m3 - 1) >> 1;                // depth-2 ancestor
    const int m1 = (m2 - 1) >> 1;                // depth-1 ancestor
    const int c0 = 2 * m3 + 1;                   // children of m3: c0, c0+1
    const int d0 = 2 * c0 + 1;                   // grandchildren: d0..d0+3 (contiguous)
    const int e0 = 2 * d0 + 1;                   // leaves: e0..e0+7 (contiguous)

    // ALL reads before ANY write (per-thread: kills the false LDS dep chain;
    // cross-thread: ancestor raws read before s==0 overwrites nodes 0..6 —
    // all 8 subtree threads of a row are in one wave, program order holds).
    const float x0 = buf[o];
    const float a1 = buf[o + m1];
    const float a2 = buf[o + m2];
    const float n3 = buf[o + m3];
    const float cA = buf[o + c0],     cB = buf[o + c0 + 1];
    const float dA = buf[o + d0],     dB = buf[o + d0 + 1];
    const float dC = buf[o + d0 + 2], dD = buf[o + d0 + 3];
    const float eA = buf[o + e0],     eB = buf[o + e0 + 1];
    const float eC = buf[o + e0 + 2], eD = buf[o + e0 + 3];
    const float eE = buf[o + e0 + 4], eF = buf[o + e0 + 5];
    const float eG = buf[o + e0 + 6], eH = buf[o + e0 + 7];

    float X2 = 0.f, X4 = 0.f, X5 = 0.f, X6 = 0.f;
    if (s == 0) {                                // reads only — still before all writes
        X2 = buf[o + 2]; X4 = buf[o + 4]; X5 = buf[o + 5]; X6 = buf[o + 6];
    }

    // ---- path-mins entirely in registers ----
    const float pm  = fminf(fminf(x0, a1), a2);  // v_min3
    const float p3  = fminf(pm, n3);
    const float pc0 = fminf(p3, cA),  pc1 = fminf(p3, cB);
    const float pd0 = fminf(pc0, dA), pd1 = fminf(pc0, dB);
    const float pd2 = fminf(pc1, dC), pd3 = fminf(pc1, dD);
    const float pe0 = fminf(pd0, eA), pe1 = fminf(pd0, eB);
    const float pe2 = fminf(pd1, eC), pe3 = fminf(pd1, eD);
    const float pe4 = fminf(pd2, eE), pe5 = fminf(pd2, eF);
    const float pe6 = fminf(pd3, eG), pe7 = fminf(pd3, eH);

    // ---- writes ----
    if (s == 0) {                                // nodes 0..6 (depths 0-2); m1==1, m2==3 here
        const float p1 = fminf(x0, a1);
        const float p2 = fminf(x0, X2);
        buf[o + 0] = sigf(x0);
        buf[o + 1] = sigf(p1);
        buf[o + 2] = sigf(p2);
        buf[o + 3] = sigf(fminf(p1, a2));
        buf[o + 4] = sigf(fminf(p1, X4));
        buf[o + 5] = sigf(fminf(p2, X5));
        buf[o + 6] = sigf(fminf(p2, X6));
    }
    buf[o + m3]     = sigf(p3);
    buf[o + c0]     = sigf(pc0); buf[o + c0 + 1] = sigf(pc1);
    buf[o + d0]     = sigf(pd0); buf[o + d0 + 1] = sigf(pd1);
    buf[o + d0 + 2] = sigf(pd2); buf[o + d0 + 3] = sigf(pd3);
    buf[o + e0]     = sigf(pe0); buf[o + e0 + 1] = sigf(pe1);
    buf[o + e0 + 2] = sigf(pe2); buf[o + e0 + 3] = sigf(pe3);
    buf[o + e0 + 4] = sigf(pe4); buf[o + e0 + 5] = sigf(pe5);
    buf[o + e0 + 6] = sigf(pe6); buf[o + e0 + 7] = sigf(pe7);
    __syncthreads();

    // ---- stage-out: coalesced float4 ----
    const float4* __restrict__ b4 = (const float4*)buf;
    float4* __restrict__ dst = (float4*)(out + base);
    #pragma unroll
    for (int k = 0; k < 3; ++k) dst[t + k * BLOCK] = b4[t + k * BLOCK];
    if (t + 3 * BLOCK < TILE_F4) dst[t + 3 * BLOCK] = b4[t + 3 * BLOCK];
}

extern "C" void kernel_launch(void* const* d_in, const int* in_sizes, int n_in,
                              void* d_out, int out_size, void* d_ws, size_t ws_size,
                              hipStream_t stream) {
    const float* x = (const float*)d_in[0];
    float* out = (float*)d_out;
    int rows = in_sizes[0] / NODES;              // 262144
    int grid = rows / RPB;                       // 8192 exactly
    dag_kernel<<<grid, BLOCK, 0, stream>>>(x, out);
}